// Round 2
// baseline (40.966 us; speedup 1.0000x reference)
//
#include <hip/hip_runtime.h>

#define BDIM 256   // reduce kernel block

// One block = one wave = 64 batch elements.
// Stage D2/D3 for the wave into LDS with coalesced float4 loads, then each
// lane reads its own element's values (element strides 25/49 are coprime with
// 32 banks -> 2 lanes/bank = conflict-free).
__global__ __launch_bounds__(64, 2) void cg_main_kernel(
    const float* __restrict__ D1, const float* __restrict__ D2,
    const float* __restrict__ D3, const float* __restrict__ cg,
    float* __restrict__ partials)
{
    __shared__ __align__(16) float s_d2[64 * 25];   // 6400 B
    __shared__ __align__(16) float s_d3[64 * 49];   // 12544 B
    __shared__ float s_cg[105];

    const int lane = threadIdx.x;        // 0..63
    const int w    = blockIdx.x;         // wave id, 4096 total

    // cg broadcast copy (105 floats)
    for (int i = lane; i < 105; i += 64) s_cg[i] = cg[i];

    // coalesced staging: wave's D2 region = 64*25 floats = 400 float4 (16B-aligned: w*6400B)
    const float4* g2 = (const float4*)(D2 + (size_t)w * (64 * 25));
    float4* l2 = (float4*)s_d2;
    #pragma unroll
    for (int k = 0; k < 7; ++k) {
        int idx = k * 64 + lane;
        if (idx < 400) l2[idx] = g2[idx];
    }
    // D3 region = 64*49 floats = 784 float4 (w*12544B, 16B-aligned)
    const float4* g3 = (const float4*)(D3 + (size_t)w * (64 * 49));
    float4* l3 = (float4*)s_d3;
    #pragma unroll
    for (int k = 0; k < 13; ++k) {
        int idx = k * 64 + lane;
        if (idx < 784) l3[idx] = g3[idx];
    }
    __syncthreads();

    const int x = w * 64 + lane;

    // D1 direct (stride 36B: only ~324 L1 transactions/wave, hidden under VALU)
    float d1[9];
    const float* p1 = D1 + (size_t)x * 9;
    #pragma unroll
    for (int i = 0; i < 9; ++i) d1[i] = p1[i];

    // U[a][j*7+c] = sum_i d1[a*3+i] * cg[i,j,c] ; all 3 a at once so each cg
    // value is ds_read exactly once (105 reads instead of 315).
    float U[3][35];
    #pragma unroll
    for (int j = 0; j < 5; ++j) {
        #pragma unroll
        for (int c = 0; c < 7; ++c) {
            const float c0 = s_cg[     j * 7 + c];
            const float c1 = s_cg[35 + j * 7 + c];
            const float c2 = s_cg[70 + j * 7 + c];
            U[0][j * 7 + c] = fmaf(d1[2], c2, fmaf(d1[1], c1, d1[0] * c0));
            U[1][j * 7 + c] = fmaf(d1[5], c2, fmaf(d1[4], c1, d1[3] * c0));
            U[2][j * 7 + c] = fmaf(d1[8], c2, fmaf(d1[7], c1, d1[6] * c0));
        }
    }

    // per-element D2/D3 from LDS (conflict-free 2-way)
    float d2[25];
    #pragma unroll
    for (int j = 0; j < 25; ++j) d2[j] = s_d2[lane * 25 + j];
    float d3[49];
    #pragma unroll
    for (int i = 0; i < 49; ++i) d3[i] = s_d3[lane * 49 + i];

    float acc = 0.0f;
    #pragma unroll
    for (int a = 0; a < 3; ++a) {
        #pragma unroll
        for (int b = 0; b < 5; ++b) {
            float cgab[7];
            #pragma unroll
            for (int i = 0; i < 7; ++i) cgab[i] = s_cg[(a * 5 + b) * 7 + i];
            #pragma unroll
            for (int c = 0; c < 7; ++c) {
                float L = d2[b * 5] * U[a][c];
                #pragma unroll
                for (int j = 1; j < 5; ++j) L = fmaf(d2[b * 5 + j], U[a][j * 7 + c], L);
                float R = cgab[0] * d3[c];
                #pragma unroll
                for (int i = 1; i < 7; ++i) R = fmaf(cgab[i], d3[i * 7 + c], R);
                const float r = L - R;
                acc = fmaf(r, r, acc);
            }
        }
    }

    // single-wave butterfly reduce
    #pragma unroll
    for (int off = 32; off > 0; off >>= 1)
        acc += __shfl_down(acc, off, 64);
    if (lane == 0) partials[w] = acc;
}

__global__ __launch_bounds__(BDIM) void cg_reduce_kernel(
    const float* __restrict__ partials, float* __restrict__ out,
    int n, float inv)
{
    const int tid = threadIdx.x;
    float s = 0.0f;
    for (int i = tid; i < n; i += BDIM) s += partials[i];   // deterministic order
    #pragma unroll
    for (int off = 32; off > 0; off >>= 1)
        s += __shfl_down(s, off, 64);
    __shared__ float wsum[BDIM / 64];
    if ((tid & 63) == 0) wsum[tid >> 6] = s;
    __syncthreads();
    if (tid == 0) {
        float t = 0.0f;
        #pragma unroll
        for (int w = 0; w < BDIM / 64; ++w) t += wsum[w];
        out[0] = t * inv;
    }
}

extern "C" void kernel_launch(void* const* d_in, const int* in_sizes, int n_in,
                              void* d_out, int out_size, void* d_ws, size_t ws_size,
                              hipStream_t stream)
{
    const float* D1 = (const float*)d_in[0];
    const float* D2 = (const float*)d_in[1];
    const float* D3 = (const float*)d_in[2];
    const float* cg = (const float*)d_in[3];
    float* out      = (float*)d_out;
    float* partials = (float*)d_ws;        // 4096 floats = 16 KB scratch

    const int batch  = in_sizes[0] / 9;    // 262144
    const int nwaves = batch / 64;         // 4096 (batch divisible by 64)
    const float inv  = 1.0f / ((float)batch * 105.0f);

    cg_main_kernel<<<nwaves, 64, 0, stream>>>(D1, D2, D3, cg, partials);
    cg_reduce_kernel<<<1, BDIM, 0, stream>>>(partials, out, nwaves, inv);
}